// Round 7
// baseline (138.053 us; speedup 1.0000x reference)
//
#include <hip/hip_runtime.h>
#include <hip/hip_bf16.h>
#include <hip/hip_fp16.h>
#include <math.h>

#define B_  4
#define S_  4096
#define D_  1024
#define M_  (B_ * S_)   // 16384 rows
#define K_  D_          // 1024 reduction
#define L_  32          // scan chunk length
#define NC_ (S_ / L_)   // 128 chunks per sequence
#define NKT 32          // K_/32 K-tiles (BK=32)

typedef __attribute__((ext_vector_type(8))) short          bf16x8;
typedef __attribute__((ext_vector_type(8))) unsigned short u16x8;
typedef __attribute__((ext_vector_type(4))) float          f32x4;

__device__ __forceinline__ unsigned short f2bf(float f) {
    union { __hip_bfloat16 h; unsigned short u; } cv;
    cv.h = __float2bfloat16(f);
    return cv.u;
}

__device__ __forceinline__ float fast_rcp(float x) {
#if __has_builtin(__builtin_amdgcn_rcpf)
    return __builtin_amdgcn_rcpf(x);
#else
    return 1.0f / x;
#endif
}

__device__ __forceinline__ void stage16(const unsigned short* src, char* dst) {
    __builtin_amdgcn_global_load_lds(
        (const __attribute__((address_space(1))) unsigned int*)src,
        (__attribute__((address_space(3))) unsigned int*)dst, 16, 0, 0);
}

// ---------------------------------------------------------------------------
// Kernel 0: fp32 -> bf16 pre-convert
// ---------------------------------------------------------------------------
__global__ __launch_bounds__(256) void to_bf16(
    const float* __restrict__ in, unsigned short* __restrict__ out, int n8)
{
    int i = blockIdx.x * 256 + threadIdx.x;
    if (i >= n8) return;
    const float4* p = (const float4*)in + (size_t)i * 2;
    float4 a = p[0], b = p[1];
    u16x8 o;
    o[0] = f2bf(a.x); o[1] = f2bf(a.y); o[2] = f2bf(a.z); o[3] = f2bf(a.w);
    o[4] = f2bf(b.x); o[5] = f2bf(b.y); o[6] = f2bf(b.z); o[7] = f2bf(b.w);
    *(u16x8*)(out + (size_t)i * 8) = o;
}

// ---------------------------------------------------------------------------
// Kernel 1: bf16 MFMA GEMM with 4-deep counted-vmcnt pipeline (T3+T4+T5+T1)
// fused with the linear-domain pointwise epilogue:
//   c = sigma(-g), v = sigma(g) * g(h),  g(h) = h>=0 ? h+0.5 : sigma(h)
// packed as __half2(c,v) -> one 4B store.
// Geometry: BM=256, BN = 128d x {h,g}, BK=32, 8 waves (2M x 4N), wave tile
// 128m x 64n. LDS = 4 bufs x 32KB (A 16KB: rows 0-255 of x; B 16KB: rows
// 0-127 hidden W, 128-255 gate W). Rows = 64B (32 bf16), slot-swizzle
// involution slot ^= (row>>1)&3 on BOTH stage-source and read (rule #21,
// verified 0 conflicts rounds 3-6).
// Schedule per tile t: 2 phases x {frag reads, stage half of t+3, bar,
// lgk0, 16 MFMA w/setprio, bar}; steady-state wait = vmcnt(8) (tiles
// t+2,t+3 in flight) -- never 0 until the 2-tile epilogue (T4).
// ---------------------------------------------------------------------------
__global__ __launch_bounds__(512, 2) void gemm_pointwise(
    const unsigned short* __restrict__ xb, const unsigned short* __restrict__ Wb,
    __half2* __restrict__ cvb)
{
    __shared__ char lds[131072];   // 4 bufs x 32KB

    const int th   = threadIdx.x;
    const int lane = th & 63;
    const int wave = th >> 6;
    const int wm = wave >> 2;      // 0..1 -> m offset 0/128
    const int wn = wave & 3;       // 0..3 -> d offset 32*wn

    const int wg  = blockIdx.x;                    // 512 wgs, 8 XCDs
    const int swz = (wg & 7) * 64 + (wg >> 3);     // bijective XCD swizzle
    const int m0 = (swz >> 3) * 256;
    const int d0 = (swz & 7) * 128;

    f32x4 acc[8][4];
#pragma unroll
    for (int i = 0; i < 8; ++i)
#pragma unroll
        for (int j = 0; j < 4; ++j)
            acc[i][j] = (f32x4){0.f, 0.f, 0.f, 0.f};

    // staging: 512 thr x 16B = 8KB = 128 rows of 64B per stage16 call
    const int srow = th >> 2;                               // 0..127
    const int scol = (((th & 3) ^ ((th >> 3) & 3)) * 8);    // pre-swizzled col
    const unsigned short* srcA  = xb + (size_t)(m0 + srow)       * K_ + scol;
    const unsigned short* srcA2 = xb + (size_t)(m0 + 128 + srow) * K_ + scol;
    const unsigned short* srcBh = Wb + (size_t)(d0 + srow)       * K_ + scol;
    const unsigned short* srcBg = Wb + (size_t)(D_ + d0 + srow)  * K_ + scol;
    char* const wuo = lds + wave * 1024;   // wave-uniform LDS dest base

    const int lr  = lane & 15;
    const int lkb = (((lane >> 4) ^ ((lr >> 1) & 3)) * 16);   // swizzled slot
    const int aoffb = (wm * 128 + lr) * 64 + lkb;             // A frag base
    const int boffb = 16384 + (wn * 32 + lr) * 64 + lkb;      // B frag base

    bf16x8 Af[4], Bf[4];

#define BAR()  asm volatile("s_barrier" ::: "memory")
#define LGK0() asm volatile("s_waitcnt lgkmcnt(0)" ::: "memory")
#define VMW(n) asm volatile("s_waitcnt vmcnt(" #n ")" ::: "memory")

#define STAGE_A(tt) do { const int ko_ = (tt) * 32;                      \
    char* d_ = wuo + ((tt) & 3) * 32768;                                 \
    stage16(srcA  + ko_, d_);                                            \
    stage16(srcA2 + ko_, d_ + 8192); } while (0)
#define STAGE_B(tt) do { const int ko_ = (tt) * 32;                      \
    char* d_ = wuo + ((tt) & 3) * 32768;                                 \
    stage16(srcBh + ko_, d_ + 16384);                                    \
    stage16(srcBg + ko_, d_ + 24576); } while (0)

#define CLUSTER(base) do {                                                \
    __builtin_amdgcn_s_setprio(1);                                        \
    _Pragma("unroll")                                                     \
    for (int i_ = 0; i_ < 4; ++i_)                                        \
        _Pragma("unroll")                                                 \
        for (int j_ = 0; j_ < 4; ++j_)                                    \
            acc[(base) + i_][j_] = __builtin_amdgcn_mfma_f32_16x16x32_bf16(\
                Af[i_], Bf[j_], acc[(base) + i_][j_], 0, 0, 0);           \
    __builtin_amdgcn_s_setprio(0);                                        \
  } while (0)

// Per-tile body: phase A computes acc[0..3] (m rows wm*128+[0,64)),
// phase B acc[4..7] (rows +64). B-frags read once, register-reused.
#define TILEBODY(T, PRE, WAITOP) do {                                     \
    const char* bc_ = lds + ((T) & 3) * 32768;                            \
    _Pragma("unroll")                                                     \
    for (int i_ = 0; i_ < 4; ++i_)                                        \
        Af[i_] = *(const bf16x8*)(bc_ + aoffb + i_ * 1024);               \
    _Pragma("unroll")                                                     \
    for (int j_ = 0; j_ < 2; ++j_) {                                      \
        Bf[j_]     = *(const bf16x8*)(bc_ + boffb + j_ * 1024);           \
        Bf[j_ + 2] = *(const bf16x8*)(bc_ + boffb + 8192 + j_ * 1024);    \
    }                                                                     \
    if (PRE) { STAGE_A((T) + 3); }                                        \
    BAR(); LGK0();                                                        \
    CLUSTER(0);                                                           \
    BAR();                                                                \
    _Pragma("unroll")                                                     \
    for (int i_ = 0; i_ < 4; ++i_)                                        \
        Af[i_] = *(const bf16x8*)(bc_ + aoffb + 4096 + i_ * 1024);        \
    if (PRE) { STAGE_B((T) + 3); }                                        \
    BAR(); LGK0();                                                        \
    CLUSTER(4);                                                           \
    WAITOP;                                                               \
    BAR();                                                                \
  } while (0)

    // prologue: stage tiles 0,1,2 (12 loads), wait tile 0 only (counted)
    STAGE_A(0); STAGE_B(0);
    STAGE_A(1); STAGE_B(1);
    STAGE_A(2); STAGE_B(2);
    VMW(8);
    BAR();

#pragma unroll 1
    for (int t = 0; t < NKT - 3; ++t)           // t = 0..28, stage t+3
        TILEBODY(t, 1, VMW(8));
    TILEBODY(NKT - 3, 0, VMW(4));               // t=29: tile 31 still flying
    TILEBODY(NKT - 2, 0, VMW(0));               // t=30: drain (loads are old)
    TILEBODY(NKT - 1, 0, (void)0);              // t=31

#undef TILEBODY
#undef CLUSTER
#undef STAGE_A
#undef STAGE_B
#undef BAR
#undef LGK0
#undef VMW

    // epilogue: linear-domain pointwise + packed half2 store
    // C/D: col = lane&15 (d), row = (lane>>4)*4 + reg (m)
#pragma unroll
    for (int mi = 0; mi < 8; ++mi)
#pragma unroll
        for (int nj = 0; nj < 2; ++nj)
#pragma unroll
            for (int r = 0; r < 4; ++r) {
                int m = m0 + wm * 128 + mi * 16 + ((lane >> 4) << 2) + r;
                int d = d0 + wn * 32 + nj * 16 + lr;
                float h = acc[mi][nj][r];         // hidden
                float g = acc[mi][nj + 2][r];     // gate, same d
                float eg  = __expf(g);            // |g| <= ~8 -> safe
                float c   = fast_rcp(1.0f + eg);  // sigma(-g) = 1 - z
                float z   = eg * c;               // sigma(g)
                float enh = __expf(-h);
                float sh  = fast_rcp(1.0f + enh); // sigma(h)
                float gh  = (h >= 0.0f) ? (h + 0.5f) : sh;
                float v   = z * gh;
                cvb[(size_t)m * D_ + d] = __floats2half2_rn(c, v);
            }
}

// ---------------------------------------------------------------------------
// Kernel 2: per-chunk reduce (linear domain, pure FMA).
// Chunk map: h_out = C * h_in + V;  C = prod c_t, V = fold fma.
// ---------------------------------------------------------------------------
__global__ __launch_bounds__(256) void chunk_reduce(
    const unsigned int* __restrict__ cvw,   // half2(c,v) as u32, [m][d]
    float2* __restrict__ CVagg)             // [b][c][d] (C,V)
{
    const int d = (blockIdx.x * 256 + threadIdx.x) * 2;
    const int c = blockIdx.y;
    const int b = blockIdx.z;
    size_t base = ((size_t)(b * S_ + c * L_)) * D_ + d;
    float C0 = 1.f, V0 = 0.f, C1 = 1.f, V1 = 0.f;
    for (int s = 0; s < L_; ++s) {
        uint2 u = *(const uint2*)(cvw + base + (size_t)s * D_);
        float2 p0 = __half22float2(*(const __half2*)&u.x);
        float2 p1 = __half22float2(*(const __half2*)&u.y);
        V0 = fmaf(p0.x, V0, p0.y);  C0 *= p0.x;
        V1 = fmaf(p1.x, V1, p1.y);  C1 *= p1.x;
    }
    size_t o = ((size_t)b * NC_ + c) * D_ + d;
    float4 st = {C0, V0, C1, V1};
    *(float4*)(CVagg + o) = st;
}

// ---------------------------------------------------------------------------
// Kernel 3: scan across chunks (128 FMA steps, tiny). P[c] = h at chunk entry.
// ---------------------------------------------------------------------------
__global__ __launch_bounds__(256) void chunk_scan(
    const float2* __restrict__ CVagg, float* __restrict__ P)
{
    const int d = blockIdx.x * 256 + threadIdx.x;
    const int b = blockIdx.z;
    float h = 0.0f;
    for (int c = 0; c < NC_; ++c) {
        size_t o = ((size_t)b * NC_ + c) * D_ + d;
        P[o] = h;
        float2 cv = CVagg[o];
        h = fmaf(cv.x, h, cv.y);
    }
}

// ---------------------------------------------------------------------------
// Kernel 4: apply — h = fma(c, h, v) from chunk-entry prefix; write fp32 out.
// ---------------------------------------------------------------------------
__global__ __launch_bounds__(256) void chunk_apply(
    const unsigned int* __restrict__ cvw, const float* __restrict__ P,
    float* __restrict__ out)
{
    const int d = (blockIdx.x * 256 + threadIdx.x) * 2;
    const int c = blockIdx.y;
    const int b = blockIdx.z;
    size_t base = ((size_t)(b * S_ + c * L_)) * D_ + d;
    float2 h2 = *(const float2*)(P + ((size_t)b * NC_ + c) * D_ + d);
    float h0 = h2.x, h1 = h2.y;
    for (int s = 0; s < L_; ++s) {
        uint2 u = *(const uint2*)(cvw + base + (size_t)s * D_);
        float2 p0 = __half22float2(*(const __half2*)&u.x);
        float2 p1 = __half22float2(*(const __half2*)&u.y);
        h0 = fmaf(p0.x, h0, p0.y);
        h1 = fmaf(p1.x, h1, p1.y);
        float2 o2 = {h0, h1};
        *(float2*)(out + base + (size_t)s * D_) = o2;
    }
}

extern "C" void kernel_launch(void* const* d_in, const int* in_sizes, int n_in,
                              void* d_out, int out_size, void* d_ws, size_t ws_size,
                              hipStream_t stream) {
    const float* x = (const float*)d_in[0];   // [B,S,D] fp32
    const float* W = (const float*)d_in[1];   // [2D,D] fp32
    float* out = (float*)d_out;               // [B,S,D] fp32

    float2* CVagg = (float2*)d_ws;                             // B*NC*D float2
    float*  P     = (float*)(CVagg + (size_t)B_ * NC_ * D_);
    __half2* cvb  = (__half2*)(P + (size_t)B_ * NC_ * D_);     // M*D half2
    unsigned short* xb = (unsigned short*)(cvb + (size_t)M_ * D_);  // M*K bf16
    unsigned short* Wb = xb + (size_t)M_ * K_;                      // 2D*K bf16

    const int nx8 = M_ * K_ / 8;
    const int nw8 = 2 * D_ * K_ / 8;
    to_bf16<<<(nx8 + 255) / 256, 256, 0, stream>>>(x, xb, nx8);
    to_bf16<<<(nw8 + 255) / 256, 256, 0, stream>>>(W, Wb, nw8);

    // 512 wgs: 64 m-tiles x 8 d-tiles, XCD-swizzled in-kernel
    gemm_pointwise<<<512, 512, 0, stream>>>(xb, Wb, cvb);

    dim3 g2(D_ / 512, NC_, B_);    // 2 x 128 x 4
    chunk_reduce<<<g2, 256, 0, stream>>>((const unsigned int*)cvb, CVagg);

    dim3 g3(D_ / 256, 1, B_);      // 4 x 1 x 4
    chunk_scan<<<g3, 256, 0, stream>>>(CVagg, P);

    chunk_apply<<<g2, 256, 0, stream>>>((const unsigned int*)cvb, P, out);
}

// Round 8
// 135.819 us; speedup vs baseline: 1.0164x; 1.0164x over previous
//
#include <hip/hip_runtime.h>
#include <hip/hip_bf16.h>
#include <hip/hip_fp16.h>
#include <math.h>

#define B_  4
#define S_  4096
#define D_  1024
#define M_  (B_ * S_)   // 16384 rows
#define K_  D_          // 1024 reduction
#define L_  32          // scan chunk length
#define NC_ (S_ / L_)   // 128 chunks per sequence
#define NKT 32          // K_/32 K-tiles (BK=32)

typedef __attribute__((ext_vector_type(8))) short          bf16x8;
typedef __attribute__((ext_vector_type(8))) unsigned short u16x8;
typedef __attribute__((ext_vector_type(4))) float          f32x4;

__device__ __forceinline__ unsigned short f2bf(float f) {
    union { __hip_bfloat16 h; unsigned short u; } cv;
    cv.h = __float2bfloat16(f);
    return cv.u;
}

__device__ __forceinline__ float fast_rcp(float x) {
#if __has_builtin(__builtin_amdgcn_rcpf)
    return __builtin_amdgcn_rcpf(x);
#else
    return 1.0f / x;
#endif
}

__device__ __forceinline__ void stage16(const unsigned short* src, char* dst) {
    __builtin_amdgcn_global_load_lds(
        (const __attribute__((address_space(1))) unsigned int*)src,
        (__attribute__((address_space(3))) unsigned int*)dst, 16, 0, 0);
}

// ---------------------------------------------------------------------------
// Kernel 0: fp32 -> bf16 pre-convert
// ---------------------------------------------------------------------------
__global__ __launch_bounds__(256) void to_bf16(
    const float* __restrict__ in, unsigned short* __restrict__ out, int n8)
{
    int i = blockIdx.x * 256 + threadIdx.x;
    if (i >= n8) return;
    const float4* p = (const float4*)in + (size_t)i * 2;
    float4 a = p[0], b = p[1];
    u16x8 o;
    o[0] = f2bf(a.x); o[1] = f2bf(a.y); o[2] = f2bf(a.z); o[3] = f2bf(a.w);
    o[4] = f2bf(b.x); o[5] = f2bf(b.y); o[6] = f2bf(b.z); o[7] = f2bf(b.w);
    *(u16x8*)(out + (size_t)i * 8) = o;
}

// ---------------------------------------------------------------------------
// Kernel 1: bf16 MFMA GEMM, wave tile 128m x 128cols (acc[8][8], 4 waves,
// 1 wave/SIMD), 4-deep counted-vmcnt LDS pipeline, fused linear-domain
// pointwise epilogue AND fused per-chunk (C,V) reduction.
//
// Rationale: wave 128x64 needed 12KB LDS frag reads per 32 MFMA -> LDS pipe
// (~1150cyc/CU/tile) ~= MFMA pipe (~1240cyc) -> util capped ~38% for any
// schedule. 128x128 reads 16KB per 64 MFMA -> ~770cyc LDS vs 1240 MFMA.
//
// Geometry: block 256m x (128d x {h,g}); 4 waves = 2m x 2n; BK=32.
// LDS buf 32KB: A[256][32]bf16 @0, B[256][32] @16384 (rows 0-127 hidden W,
// 128-255 gate W). Rows 64B, slot-swizzle involution slot^=(row>>1)&3 on
// both stage-source and read (verified 0 conflicts rounds 3-7).
// Epilogue: c = sigma(-g), v = sigma(g)*g(h); cvb half2(c,v); chunk maps
// composed in-register (r-fold, shfl_xor 16/32 lq-compose, mi-pair) ->
// CVagg float2(C,V) per 32-row chunk, replacing the chunk_reduce kernel.
// ---------------------------------------------------------------------------
__global__ __launch_bounds__(256, 1) void gemm_pointwise(
    const unsigned short* __restrict__ xb, const unsigned short* __restrict__ Wb,
    __half2* __restrict__ cvb, float2* __restrict__ CVagg)
{
    __shared__ char lds[131072];   // 4 bufs x 32KB

    const int th   = threadIdx.x;
    const int lane = th & 63;
    const int wave = th >> 6;      // 0..3
    const int wm = wave >> 1;      // 0..1 -> m offset 0/128
    const int wn = wave & 1;       // 0..1 -> d offset 0/64

    const int wg  = blockIdx.x;                    // 512 wgs, 8 XCDs
    const int swz = (wg & 7) * 64 + (wg >> 3);     // bijective XCD swizzle
    const int m0 = (swz >> 3) * 256;
    const int d0 = (swz & 7) * 128;

    f32x4 acc[8][8];
#pragma unroll
    for (int i = 0; i < 8; ++i)
#pragma unroll
        for (int j = 0; j < 8; ++j)
            acc[i][j] = (f32x4){0.f, 0.f, 0.f, 0.f};

    // staging: 256 thr x 16B = 4KB = 64 rows of 64B per stage16 call
    const int srow = th >> 2;                               // 0..63
    const int scol = (((th & 3) ^ ((th >> 3) & 3)) * 8);    // pre-swizzled col
    const unsigned short* srcA  = xb + (size_t)(m0 + srow)      * K_ + scol;
    const unsigned short* srcBh = Wb + (size_t)(d0 + srow)      * K_ + scol;
    const unsigned short* srcBg = Wb + (size_t)(D_ + d0 + srow) * K_ + scol;
    char* const wuo = lds + wave * 1024;   // wave-uniform LDS dest base

    const int lr = lane & 15;
    const int lq = lane >> 4;
    const int lkb = ((lq ^ ((lr >> 1) & 3)) * 16);            // swizzled slot
    const int aoffb = (wm * 128 + lr) * 64 + lkb;             // A frag base
    const int boffb = 16384 + (wn * 64 + lr) * 64 + lkb;      // B frag base

    bf16x8 Af[8], Bf[8];

#define BAR()  asm volatile("s_barrier" ::: "memory")
#define VMW(n) asm volatile("s_waitcnt vmcnt(" #n ")" ::: "memory")

#define STAGE(tt) do { const int ko_ = (tt) * 32;                        \
    char* d_ = wuo + ((tt) & 3) * 32768;                                 \
    stage16(srcA  + ko_,              d_);                               \
    stage16(srcA  + 64 * K_  + ko_,   d_ + 4096);                        \
    stage16(srcA  + 128 * K_ + ko_,   d_ + 8192);                        \
    stage16(srcA  + 192 * K_ + ko_,   d_ + 12288);                       \
    stage16(srcBh + ko_,              d_ + 16384);                       \
    stage16(srcBh + 64 * K_  + ko_,   d_ + 20480);                       \
    stage16(srcBg + ko_,              d_ + 24576);                       \
    stage16(srcBg + 64 * K_  + ko_,   d_ + 28672);                       \
  } while (0)

// Per-tile: read all 16 frags (compiler inserts counted lgkmcnt before
// first dependent MFMA), issue next stage, 64 MFMA, counted vmcnt, barrier.
#define TILEBODY(T, PRE, WAITOP) do {                                     \
    const char* bc_ = lds + ((T) & 3) * 32768;                            \
    _Pragma("unroll")                                                     \
    for (int i_ = 0; i_ < 8; ++i_)                                        \
        Af[i_] = *(const bf16x8*)(bc_ + aoffb + i_ * 1024);               \
    _Pragma("unroll")                                                     \
    for (int j_ = 0; j_ < 4; ++j_) {                                      \
        Bf[j_]     = *(const bf16x8*)(bc_ + boffb + j_ * 1024);           \
        Bf[j_ + 4] = *(const bf16x8*)(bc_ + boffb + 8192 + j_ * 1024);    \
    }                                                                     \
    if (PRE) { STAGE((T) + 3); }                                          \
    _Pragma("unroll")                                                     \
    for (int i_ = 0; i_ < 8; ++i_)                                        \
        _Pragma("unroll")                                                 \
        for (int j_ = 0; j_ < 8; ++j_)                                    \
            acc[i_][j_] = __builtin_amdgcn_mfma_f32_16x16x32_bf16(        \
                Af[i_], Bf[j_], acc[i_][j_], 0, 0, 0);                    \
    WAITOP;                                                               \
    BAR();                                                                \
  } while (0)

    // prologue: stage tiles 0,1,2 (24 loads), wait tile 0 only (counted)
    STAGE(0); STAGE(1); STAGE(2);
    VMW(16);
    BAR();

#pragma unroll 1
    for (int t = 0; t < NKT - 3; ++t)           // t = 0..28, stage t+3
        TILEBODY(t, 1, VMW(16));
    TILEBODY(NKT - 3, 0, VMW(8));               // t=29
    TILEBODY(NKT - 2, 0, VMW(0));               // t=30
    TILEBODY(NKT - 1, 0, (void)0);              // t=31

#undef TILEBODY
#undef STAGE
#undef BAR
#undef VMW

    // ---- epilogue: pointwise + cvb store + fused chunk-(C,V) reduction ----
    // C/D: col = lane&15 (d), row = lq*4 + reg (m). Lane rows for frag mi:
    // wm*128 + mi*16 + lq*4 + {0..3}. Chunk (32 rows) = mi pair, composed
    // r-fold -> lq-compose (shfl_xor 16,32) -> mi-pair.
#pragma unroll
    for (int mp = 0; mp < 4; ++mp) {          // mi pair (2mp, 2mp+1)
        float C16[2][4], V16[2][4];
#pragma unroll
        for (int hf = 0; hf < 2; ++hf) {
            const int mi = mp * 2 + hf;
#pragma unroll
            for (int nj = 0; nj < 4; ++nj) {
                float C4 = 1.0f, V4 = 0.0f;
                const int d = d0 + wn * 64 + nj * 16 + lr;
#pragma unroll
                for (int r = 0; r < 4; ++r) {
                    int m = m0 + wm * 128 + mi * 16 + lq * 4 + r;
                    float h = acc[mi][nj][r];         // hidden
                    float g = acc[mi][nj + 4][r];     // gate, same d
                    float eg  = __expf(g);
                    float c   = fast_rcp(1.0f + eg);  // sigma(-g)
                    float z   = eg * c;               // sigma(g)
                    float enh = __expf(-h);
                    float sh  = fast_rcp(1.0f + enh); // sigma(h)
                    float gh  = (h >= 0.0f) ? (h + 0.5f) : sh;
                    float v   = z * gh;
                    cvb[(size_t)m * D_ + d] = __floats2half2_rn(c, v);
                    V4 = fmaf(c, V4, v);              // compose ascending r
                    C4 *= c;
                }
                // lq-compose (rows base+lq*4, ascending lq):
                float Ca = __shfl_xor(C4, 16), Va = __shfl_xor(V4, 16);
                float Clo = (lq & 1) ? Ca : C4, Vlo = (lq & 1) ? Va : V4;
                float Chi = (lq & 1) ? C4 : Ca, Vhi = (lq & 1) ? V4 : Va;
                float C2 = Clo * Chi, V2 = fmaf(Chi, Vlo, Vhi);
                float Cb = __shfl_xor(C2, 32), Vb = __shfl_xor(V2, 32);
                float Cl2 = (lq & 2) ? Cb : C2, Vl2 = (lq & 2) ? Vb : V2;
                float Ch2 = (lq & 2) ? C2 : Cb, Vh2 = (lq & 2) ? V2 : Vb;
                C16[hf][nj] = Cl2 * Ch2;
                V16[hf][nj] = fmaf(Ch2, Vl2, Vh2);
            }
        }
        if (lq == 0) {
            const int chunkg = (m0 + wm * 128 + mp * 32) >> 5;  // global chunk
#pragma unroll
            for (int nj = 0; nj < 4; ++nj) {
                float C32 = C16[0][nj] * C16[1][nj];
                float V32 = fmaf(C16[1][nj], V16[0][nj], V16[1][nj]);
                const int d = d0 + wn * 64 + nj * 16 + lr;
                float2 st; st.x = C32; st.y = V32;
                CVagg[(size_t)chunkg * D_ + d] = st;
            }
        }
    }
}

// ---------------------------------------------------------------------------
// Kernel 3: scan across chunks (128 FMA steps, tiny). P[c] = h at chunk entry.
// ---------------------------------------------------------------------------
__global__ __launch_bounds__(256) void chunk_scan(
    const float2* __restrict__ CVagg, float* __restrict__ P)
{
    const int d = blockIdx.x * 256 + threadIdx.x;
    const int b = blockIdx.z;
    float h = 0.0f;
    for (int c = 0; c < NC_; ++c) {
        size_t o = ((size_t)b * NC_ + c) * D_ + d;
        P[o] = h;
        float2 cv = CVagg[o];
        h = fmaf(cv.x, h, cv.y);
    }
}

// ---------------------------------------------------------------------------
// Kernel 4: apply — h = fma(c, h, v) from chunk-entry prefix; write fp32 out.
// ---------------------------------------------------------------------------
__global__ __launch_bounds__(256) void chunk_apply(
    const unsigned int* __restrict__ cvw, const float* __restrict__ P,
    float* __restrict__ out)
{
    const int d = (blockIdx.x * 256 + threadIdx.x) * 2;
    const int c = blockIdx.y;
    const int b = blockIdx.z;
    size_t base = ((size_t)(b * S_ + c * L_)) * D_ + d;
    float2 h2 = *(const float2*)(P + ((size_t)b * NC_ + c) * D_ + d);
    float h0 = h2.x, h1 = h2.y;
    for (int s = 0; s < L_; ++s) {
        uint2 u = *(const uint2*)(cvw + base + (size_t)s * D_);
        float2 p0 = __half22float2(*(const __half2*)&u.x);
        float2 p1 = __half22float2(*(const __half2*)&u.y);
        h0 = fmaf(p0.x, h0, p0.y);
        h1 = fmaf(p1.x, h1, p1.y);
        float2 o2 = {h0, h1};
        *(float2*)(out + base + (size_t)s * D_) = o2;
    }
}

extern "C" void kernel_launch(void* const* d_in, const int* in_sizes, int n_in,
                              void* d_out, int out_size, void* d_ws, size_t ws_size,
                              hipStream_t stream) {
    const float* x = (const float*)d_in[0];   // [B,S,D] fp32
    const float* W = (const float*)d_in[1];   // [2D,D] fp32
    float* out = (float*)d_out;               // [B,S,D] fp32

    float2* CVagg = (float2*)d_ws;                             // B*NC*D float2
    float*  P     = (float*)(CVagg + (size_t)B_ * NC_ * D_);
    __half2* cvb  = (__half2*)(P + (size_t)B_ * NC_ * D_);     // M*D half2
    unsigned short* xb = (unsigned short*)(cvb + (size_t)M_ * D_);  // M*K bf16
    unsigned short* Wb = xb + (size_t)M_ * K_;                      // 2D*K bf16

    const int nx8 = M_ * K_ / 8;
    const int nw8 = 2 * D_ * K_ / 8;
    to_bf16<<<(nx8 + 255) / 256, 256, 0, stream>>>(x, xb, nx8);
    to_bf16<<<(nw8 + 255) / 256, 256, 0, stream>>>(W, Wb, nw8);

    // 512 wgs: 64 m-tiles x 8 d-tiles, XCD-swizzled in-kernel
    gemm_pointwise<<<512, 256, 0, stream>>>(xb, Wb, cvb, CVagg);

    dim3 g3(D_ / 256, 1, B_);      // 4 x 1 x 4
    chunk_scan<<<g3, 256, 0, stream>>>(CVagg, P);

    dim3 g2(D_ / 512, NC_, B_);    // 2 x 128 x 4
    chunk_apply<<<g2, 256, 0, stream>>>((const unsigned int*)cvb, P, out);
}

// Round 9
// 127.501 us; speedup vs baseline: 1.0828x; 1.0652x over previous
//
#include <hip/hip_runtime.h>
#include <hip/hip_bf16.h>
#include <hip/hip_fp16.h>
#include <math.h>

#define B_  4
#define S_  4096
#define D_  1024
#define M_  (B_ * S_)   // 16384 rows
#define K_  D_          // 1024 reduction
#define L_  32          // scan chunk length
#define NC_ (S_ / L_)   // 128 chunks per sequence
#define NKT 16          // K_/64 K-tiles (BK=64)

typedef __attribute__((ext_vector_type(8))) short          bf16x8;
typedef __attribute__((ext_vector_type(8))) unsigned short u16x8;
typedef __attribute__((ext_vector_type(4))) float          f32x4;

__device__ __forceinline__ unsigned short f2bf(float f) {
    union { __hip_bfloat16 h; unsigned short u; } cv;
    cv.h = __float2bfloat16(f);
    return cv.u;
}

__device__ __forceinline__ float fast_rcp(float x) {
#if __has_builtin(__builtin_amdgcn_rcpf)
    return __builtin_amdgcn_rcpf(x);
#else
    return 1.0f / x;
#endif
}

__device__ __forceinline__ void stage16(const unsigned short* src, char* dst) {
    __builtin_amdgcn_global_load_lds(
        (const __attribute__((address_space(1))) unsigned int*)src,
        (__attribute__((address_space(3))) unsigned int*)dst, 16, 0, 0);
}

// ---------------------------------------------------------------------------
// Kernel 0: fp32 -> bf16 pre-convert
// ---------------------------------------------------------------------------
__global__ __launch_bounds__(256) void to_bf16(
    const float* __restrict__ in, unsigned short* __restrict__ out, int n8)
{
    int i = blockIdx.x * 256 + threadIdx.x;
    if (i >= n8) return;
    const float4* p = (const float4*)in + (size_t)i * 2;
    float4 a = p[0], b = p[1];
    u16x8 o;
    o[0] = f2bf(a.x); o[1] = f2bf(a.y); o[2] = f2bf(a.z); o[3] = f2bf(a.w);
    o[4] = f2bf(b.x); o[5] = f2bf(b.y); o[6] = f2bf(b.z); o[7] = f2bf(b.w);
    *(u16x8*)(out + (size_t)i * 8) = o;
}

// ---------------------------------------------------------------------------
// Kernel 1: round-6 GEMM core (best measured: 73us, MfmaUtil 38.5%) +
// round-8's verified fused chunk-(C,V) reduction epilogue.
// BM=256, BN=128d x {h,g}, BK=64, 8 waves (2M x 4N), wave tile 128m x 64c,
// 2-deep LDS (2 x 64KB), 8-phase schedule.
// Epilogue: c = sigma(-g), v = sigma(g)*g(h); cvb half2(c,v) per element;
// per-32-row-chunk affine maps composed in-register (r-fold, shfl_xor 16/32
// lq-compose, mi-pair) -> CVagg float2(C,V), replacing chunk_reduce kernel.
// ---------------------------------------------------------------------------
__global__ __launch_bounds__(512, 2) void gemm_pointwise(
    const unsigned short* __restrict__ xb, const unsigned short* __restrict__ Wb,
    __half2* __restrict__ cvb, float2* __restrict__ CVagg)
{
    __shared__ char lds[131072];   // 2 x 64KB

    const int th   = threadIdx.x;
    const int lane = th & 63;
    const int wave = th >> 6;
    const int wm = wave >> 2;      // 0..1 -> m offset 0/128
    const int wn = wave & 3;       // 0..3 -> d offset 32*wn

    const int wg  = blockIdx.x;                    // 512 wgs, 8 XCDs
    const int swz = (wg & 7) * 64 + (wg >> 3);     // bijective XCD swizzle
    const int m0 = (swz >> 3) * 256;
    const int d0 = (swz & 7) * 128;

    f32x4 acc[8][4];
#pragma unroll
    for (int i = 0; i < 8; ++i)
#pragma unroll
        for (int j = 0; j < 4; ++j)
            acc[i][j] = (f32x4){0.f, 0.f, 0.f, 0.f};

    // staging: 512 thr x 16B = 8KB = 128 rows per round; 8 rounds per K-tile
    const int srow = th >> 2;                               // 0..127
    const int scol = (((th & 3) ^ ((th >> 3) & 3)) * 8);    // pre-swizzled col
    const unsigned short* srcA  = xb + (size_t)(m0 + srow)       * K_ + scol;
    const unsigned short* srcA2 = xb + (size_t)(m0 + 128 + srow) * K_ + scol;
    const unsigned short* srcBh = Wb + (size_t)(d0 + srow)       * K_ + scol;
    const unsigned short* srcBg = Wb + (size_t)(D_ + d0 + srow)  * K_ + scol;
    char* const wuo = lds + wave * 1024;   // wave-uniform LDS dest base

    const int lr = lane & 15;
    const int lq = lane >> 4;
    const int lkb = ((lq ^ ((lr >> 1) & 3)) * 16);            // swizzled slot
    const int aoffb = (wm * 128 + lr) * 64 + lkb;             // A frag base
    const int boffb = 32768 + (wn * 32 + lr) * 64 + lkb;      // B frag base

    bf16x8 Aa[4], Ab[4], Ba[4], Bb[4];

#define BAR()  asm volatile("s_barrier" ::: "memory")
#define LGK0() asm volatile("s_waitcnt lgkmcnt(0)" ::: "memory")
#define VM0()  asm volatile("s_waitcnt vmcnt(0)" ::: "memory")

#define CLUSTER(base, AF, BF) do {                                        \
    __builtin_amdgcn_s_setprio(1);                                        \
    _Pragma("unroll")                                                     \
    for (int i_ = 0; i_ < 4; ++i_)                                        \
        _Pragma("unroll")                                                 \
        for (int j_ = 0; j_ < 4; ++j_)                                    \
            acc[(base) + i_][j_] = __builtin_amdgcn_mfma_f32_16x16x32_bf16(\
                AF[i_], BF[j_], acc[(base) + i_][j_], 0, 0, 0);           \
    __builtin_amdgcn_s_setprio(0);                                        \
  } while (0)

    // prologue: stage tile 0 into buf0, drain, read phase-0 frags
    stage16(srcA,       wuo + 0);
    stage16(srcA2,      wuo + 8192);
    stage16(srcA  + 32, wuo + 16384);
    stage16(srcA2 + 32, wuo + 24576);
    stage16(srcBh,      wuo + 32768);
    stage16(srcBg,      wuo + 40960);
    stage16(srcBh + 32, wuo + 49152);
    stage16(srcBg + 32, wuo + 57344);
    VM0();
    BAR();
    {
        const char* bc = lds;
#pragma unroll
        for (int i = 0; i < 4; ++i)
            Aa[i] = *(const bf16x8*)(bc + aoffb + i * 1024);
#pragma unroll
        for (int j = 0; j < 2; ++j) {
            Ba[j]     = *(const bf16x8*)(bc + boffb + j * 1024);
            Ba[j + 2] = *(const bf16x8*)(bc + boffb + 8192 + j * 1024);
        }
    }

#pragma unroll 1
    for (int t = 0; t < NKT; ++t) {
        const char* bc  = lds + (t & 1) * 65536;        // compute buf (read)
        char*       bn  = wuo + ((t + 1) & 1) * 65536;  // next buf (stage dest)
        const char* bnr = lds + ((t + 1) & 1) * 65536;  // next buf (read)
        const int kof = (t + 1) * 64;
        const bool pre = (t < NKT - 1);

        // ---- phase 0: MFMA acc[0..3] = A(mh0,k0) x B(k0) ----
#pragma unroll
        for (int i = 0; i < 4; ++i)
            Ab[i] = *(const bf16x8*)(bc + aoffb + 4096 + i * 1024);    // (mh1,k0)
        if (pre) {
            stage16(srcA  + kof,      bn + 0);
            stage16(srcA2 + kof,      bn + 8192);
            stage16(srcA  + kof + 32, bn + 16384);
            stage16(srcA2 + kof + 32, bn + 24576);
        }
        BAR(); LGK0();
        CLUSTER(0, Aa, Ba);
        BAR();

        // ---- phase 1: MFMA acc[4..7] = A(mh1,k0) x B(k0) ----
#pragma unroll
        for (int i = 0; i < 4; ++i)
            Aa[i] = *(const bf16x8*)(bc + aoffb + 16384 + i * 1024);   // (mh0,k1)
#pragma unroll
        for (int j = 0; j < 2; ++j) {
            Bb[j]     = *(const bf16x8*)(bc + boffb + 16384 + j * 1024);         // B(k1) h
            Bb[j + 2] = *(const bf16x8*)(bc + boffb + 16384 + 8192 + j * 1024);  // B(k1) g
        }
        if (pre) {
            stage16(srcBh + kof,      bn + 32768);
            stage16(srcBg + kof,      bn + 40960);
            stage16(srcBh + kof + 32, bn + 49152);
            stage16(srcBg + kof + 32, bn + 57344);
        }
        BAR(); LGK0();
        CLUSTER(4, Ab, Ba);
        BAR();

        // ---- phase 2: MFMA acc[0..3] = A(mh0,k1) x B(k1) ----
#pragma unroll
        for (int i = 0; i < 4; ++i)
            Ab[i] = *(const bf16x8*)(bc + aoffb + 4096 + 16384 + i * 1024);  // (mh1,k1)
        BAR(); LGK0();
        CLUSTER(0, Aa, Bb);
        BAR();

        // ---- phase 3: cross-buf sync, prefetch next frags, last cluster ----
        VM0();           // t+1's 8 loads issued >=2 phases ago -> cheap drain
        BAR();           // buf[(t+1)&1] now globally valid
        if (pre) {       // issue next tile's phase-0 frag reads BEFORE MFMAs
#pragma unroll
            for (int i = 0; i < 4; ++i)
                Aa[i] = *(const bf16x8*)(bnr + aoffb + i * 1024);
#pragma unroll
            for (int j = 0; j < 2; ++j) {
                Ba[j]     = *(const bf16x8*)(bnr + boffb + j * 1024);
                Ba[j + 2] = *(const bf16x8*)(bnr + boffb + 8192 + j * 1024);
            }
        }
        CLUSTER(4, Ab, Bb);
        // no trailing barrier: next phase-0 stages into buf[t&1], which no
        // wave reads after phase 2's closing barrier (phase 3 = regs + bnr)
    }
#undef CLUSTER
#undef BAR
#undef LGK0
#undef VM0

    // ---- epilogue: pointwise + cvb store + fused chunk-(C,V) reduction ----
    // C/D: col = lane&15 (d), row = lq*4 + reg (m). Lane rows for frag mi:
    // wm*128 + mi*16 + lq*4 + {0..3}. Chunk (32 rows) = mi pair; compose
    // r-fold -> lq-compose (shfl_xor 16,32) -> mi-pair; write at lq==0.
#pragma unroll
    for (int mp = 0; mp < 4; ++mp) {          // mi pair (2mp, 2mp+1)
        float C16[2][2], V16[2][2];
#pragma unroll
        for (int hf = 0; hf < 2; ++hf) {
            const int mi = mp * 2 + hf;
#pragma unroll
            for (int nj = 0; nj < 2; ++nj) {
                float C4 = 1.0f, V4 = 0.0f;
                const int d = d0 + wn * 32 + nj * 16 + lr;
#pragma unroll
                for (int r = 0; r < 4; ++r) {
                    int m = m0 + wm * 128 + mi * 16 + lq * 4 + r;
                    float h = acc[mi][nj][r];         // hidden
                    float g = acc[mi][nj + 2][r];     // gate, same d
                    float eg  = __expf(g);
                    float c   = fast_rcp(1.0f + eg);  // sigma(-g)
                    float z   = eg * c;               // sigma(g)
                    float enh = __expf(-h);
                    float sh  = fast_rcp(1.0f + enh); // sigma(h)
                    float gh  = (h >= 0.0f) ? (h + 0.5f) : sh;
                    float v   = z * gh;
                    cvb[(size_t)m * D_ + d] = __floats2half2_rn(c, v);
                    V4 = fmaf(c, V4, v);              // compose ascending r
                    C4 *= c;
                }
                // lq-compose (rows base+lq*4, ascending lq):
                float Ca = __shfl_xor(C4, 16), Va = __shfl_xor(V4, 16);
                float Clo = (lq & 1) ? Ca : C4, Vlo = (lq & 1) ? Va : V4;
                float Chi = (lq & 1) ? C4 : Ca, Vhi = (lq & 1) ? V4 : Va;
                float C2 = Clo * Chi, V2 = fmaf(Chi, Vlo, Vhi);
                float Cb = __shfl_xor(C2, 32), Vb = __shfl_xor(V2, 32);
                float Cl2 = (lq & 2) ? Cb : C2, Vl2 = (lq & 2) ? Vb : V2;
                float Ch2 = (lq & 2) ? C2 : Cb, Vh2 = (lq & 2) ? V2 : Vb;
                C16[hf][nj] = Cl2 * Ch2;
                V16[hf][nj] = fmaf(Ch2, Vl2, Vh2);
            }
        }
        if (lq == 0) {
            const int chunkg = (m0 + wm * 128 + mp * 32) >> 5;  // global chunk
#pragma unroll
            for (int nj = 0; nj < 2; ++nj) {
                float C32 = C16[0][nj] * C16[1][nj];
                float V32 = fmaf(C16[1][nj], V16[0][nj], V16[1][nj]);
                const int d = d0 + wn * 32 + nj * 16 + lr;
                float2 st; st.x = C32; st.y = V32;
                CVagg[(size_t)chunkg * D_ + d] = st;
            }
        }
    }
}

// ---------------------------------------------------------------------------
// Kernel 3: scan across chunks (128 FMA steps, tiny). P[c] = h at chunk entry.
// ---------------------------------------------------------------------------
__global__ __launch_bounds__(256) void chunk_scan(
    const float2* __restrict__ CVagg, float* __restrict__ P)
{
    const int d = blockIdx.x * 256 + threadIdx.x;
    const int b = blockIdx.z;
    float h = 0.0f;
    for (int c = 0; c < NC_; ++c) {
        size_t o = ((size_t)b * NC_ + c) * D_ + d;
        P[o] = h;
        float2 cv = CVagg[o];
        h = fmaf(cv.x, h, cv.y);
    }
}

// ---------------------------------------------------------------------------
// Kernel 4: apply — h = fma(c, h, v) from chunk-entry prefix; write fp32 out.
// ---------------------------------------------------------------------------
__global__ __launch_bounds__(256) void chunk_apply(
    const unsigned int* __restrict__ cvw, const float* __restrict__ P,
    float* __restrict__ out)
{
    const int d = (blockIdx.x * 256 + threadIdx.x) * 2;
    const int c = blockIdx.y;
    const int b = blockIdx.z;
    size_t base = ((size_t)(b * S_ + c * L_)) * D_ + d;
    float2 h2 = *(const float2*)(P + ((size_t)b * NC_ + c) * D_ + d);
    float h0 = h2.x, h1 = h2.y;
    for (int s = 0; s < L_; ++s) {
        uint2 u = *(const uint2*)(cvw + base + (size_t)s * D_);
        float2 p0 = __half22float2(*(const __half2*)&u.x);
        float2 p1 = __half22float2(*(const __half2*)&u.y);
        h0 = fmaf(p0.x, h0, p0.y);
        h1 = fmaf(p1.x, h1, p1.y);
        float2 o2 = {h0, h1};
        *(float2*)(out + base + (size_t)s * D_) = o2;
    }
}

extern "C" void kernel_launch(void* const* d_in, const int* in_sizes, int n_in,
                              void* d_out, int out_size, void* d_ws, size_t ws_size,
                              hipStream_t stream) {
    const float* x = (const float*)d_in[0];   // [B,S,D] fp32
    const float* W = (const float*)d_in[1];   // [2D,D] fp32
    float* out = (float*)d_out;               // [B,S,D] fp32

    float2* CVagg = (float2*)d_ws;                             // B*NC*D float2
    float*  P     = (float*)(CVagg + (size_t)B_ * NC_ * D_);
    __half2* cvb  = (__half2*)(P + (size_t)B_ * NC_ * D_);     // M*D half2
    unsigned short* xb = (unsigned short*)(cvb + (size_t)M_ * D_);  // M*K bf16
    unsigned short* Wb = xb + (size_t)M_ * K_;                      // 2D*K bf16

    const int nx8 = M_ * K_ / 8;
    const int nw8 = 2 * D_ * K_ / 8;
    to_bf16<<<(nx8 + 255) / 256, 256, 0, stream>>>(x, xb, nx8);
    to_bf16<<<(nw8 + 255) / 256, 256, 0, stream>>>(W, Wb, nw8);

    // 512 wgs: 64 m-tiles x 8 d-tiles, XCD-swizzled in-kernel
    gemm_pointwise<<<512, 512, 0, stream>>>(xb, Wb, cvb, CVagg);

    dim3 g3(D_ / 256, 1, B_);      // 4 x 1 x 4
    chunk_scan<<<g3, 256, 0, stream>>>(CVagg, P);

    dim3 g2(D_ / 512, NC_, B_);    // 2 x 128 x 4
    chunk_apply<<<g2, 256, 0, stream>>>((const unsigned int*)cvb, P, out);
}